// Round 18
// baseline (159.906 us; speedup 1.0000x reference)
//
#include <hip/hip_runtime.h>

// Problem constants
#define B_ 32
#define N_ 4096
#define C_ 768
#define H_ 8
#define DH_ 96
#define NSL 32               // slices per batch row (128 rows each)
#define RPS (N_ / NSL)       // 128
#define NDG 4                // d-groups in prep

#define BARL() do { asm volatile("s_waitcnt lgkmcnt(0)" ::: "memory"); \
                    __builtin_amdgcn_s_barrier(); } while (0)

// ---- prep: grid (H, NDG) = 32 blocks (R17-validated) ----------------------
__global__ __launch_bounds__(256) void k_prep(const float* __restrict__ queries,
    const float* __restrict__ Wq, const float* __restrict__ Wkv,
    float* __restrict__ wqep) {
  __shared__ float qh[24];
  const int h = blockIdx.x, dg = blockIdx.y;
  const int tid = threadIdx.x, lane = tid & 63, wv = tid >> 6;
  const int d0 = dg * 24;

  float4 q0 = *(const float4*)(queries + lane * 4);
  float4 q1 = *(const float4*)(queries + 256 + lane * 4);
  float4 q2 = *(const float4*)(queries + 512 + lane * 4);
#pragma unroll
  for (int j = 0; j < 6; ++j) {
    int dl = wv * 6 + j;
    const float* wr = Wq + (size_t)(h * DH_ + d0 + dl) * C_ + lane * 4;
    float4 w0 = *(const float4*)(wr);
    float4 w1 = *(const float4*)(wr + 256);
    float4 w2 = *(const float4*)(wr + 512);
    float a = w0.x * q0.x;
    a = fmaf(w0.y, q0.y, a); a = fmaf(w0.z, q0.z, a); a = fmaf(w0.w, q0.w, a);
    a = fmaf(w1.x, q1.x, a); a = fmaf(w1.y, q1.y, a);
    a = fmaf(w1.z, q1.z, a); a = fmaf(w1.w, q1.w, a);
    a = fmaf(w2.x, q2.x, a); a = fmaf(w2.y, q2.y, a);
    a = fmaf(w2.z, q2.z, a); a = fmaf(w2.w, q2.w, a);
#pragma unroll
    for (int off = 32; off; off >>= 1) a += __shfl_xor(a, off);
    if (lane == 0) qh[dl] = a;
  }
  __syncthreads();

  const int c0 = tid * 3;
  const float* base = Wkv + (size_t)(h * DH_ + d0) * C_ + c0;
  float a0 = 0.f, a1 = 0.f, a2 = 0.f;
#pragma unroll 8
  for (int d = 0; d < 24; ++d) {
    float qd = qh[d];
    const float* p = base + (size_t)d * C_;
    a0 = fmaf(qd, p[0], a0);
    a1 = fmaf(qd, p[1], a1);
    a2 = fmaf(qd, p[2], a2);
  }
  float* o = wqep + ((size_t)dg * H_ + h) * C_ + c0;
  o[0] = a0; o[1] = a1; o[2] = a2;
}

// ---- barrier-free streaming fused pass ------------------------------------
// grid (NSL, B_) = 1024 blocks x 256 threads = 4096 waves = 16 waves/CU
// (4/SIMD). Block = 4 waves sharing one 128-row slice; wave w owns heads
// {2w, 2w+1}. Zero LDS, no phase barriers; BARL every 16 rows only bounds
// wave drift so the 4x row re-reads stay L1/L2-hot. ~95 VGPR (no spill).
__global__ __launch_bounds__(256) void k_stream(
    const float* __restrict__ x, const float* __restrict__ wqep,
    float* __restrict__ part, float* __restrict__ sout) {
  const int lane = threadIdx.x & 63, wid = threadIdx.x >> 6;
  const int sl = blockIdx.x, b = blockIdx.y;
  const int h0 = wid * 2;
  const int col = lane * 4;
  const int l1 = lane & 1;

  // wq for this wave's two heads: sum NDG prep partials (one-time)
  float4 wq[2][3];
#pragma unroll
  for (int hh = 0; hh < 2; ++hh)
#pragma unroll
    for (int p = 0; p < 3; ++p) {
      float4 s = *(const float4*)(wqep + (size_t)(h0 + hh) * C_ + p * 256 + col);
#pragma unroll
      for (int dg = 1; dg < NDG; ++dg) {
        float4 v = *(const float4*)(wqep + ((size_t)dg * H_ + h0 + hh) * C_ + p * 256 + col);
        s.x += v.x; s.y += v.y; s.z += v.z; s.w += v.w;
      }
      wq[hh][p] = s;
    }

  float4 acc[2][3];
#pragma unroll
  for (int hh = 0; hh < 2; ++hh)
#pragma unroll
    for (int p = 0; p < 3; ++p) acc[hh][p] = make_float4(0.f, 0.f, 0.f, 0.f);
  float sreg = 0.f;   // even lanes: denom h0; odd lanes: denom h0+1

  const float* xr = x + ((size_t)b * N_ + (size_t)sl * RPS) * C_ + col;

#define LOADROW(BUF, R) do {                                        \
    const float* rp_ = xr + (size_t)(R) * C_;                       \
    BUF[0] = *(const float4*)(rp_);                                 \
    BUF[1] = *(const float4*)(rp_ + 256);                           \
    BUF[2] = *(const float4*)(rp_ + 512);                           \
  } while (0)

#define PROC(XV) do {                                               \
    float d0_, d1_;                                                 \
    d0_  = XV[0].x * wq[0][0].x;     d1_  = XV[0].x * wq[1][0].x;   \
    d0_ = fmaf(XV[0].y, wq[0][0].y, d0_); d1_ = fmaf(XV[0].y, wq[1][0].y, d1_); \
    d0_ = fmaf(XV[0].z, wq[0][0].z, d0_); d1_ = fmaf(XV[0].z, wq[1][0].z, d1_); \
    d0_ = fmaf(XV[0].w, wq[0][0].w, d0_); d1_ = fmaf(XV[0].w, wq[1][0].w, d1_); \
    d0_ = fmaf(XV[1].x, wq[0][1].x, d0_); d1_ = fmaf(XV[1].x, wq[1][1].x, d1_); \
    d0_ = fmaf(XV[1].y, wq[0][1].y, d0_); d1_ = fmaf(XV[1].y, wq[1][1].y, d1_); \
    d0_ = fmaf(XV[1].z, wq[0][1].z, d0_); d1_ = fmaf(XV[1].z, wq[1][1].z, d1_); \
    d0_ = fmaf(XV[1].w, wq[0][1].w, d0_); d1_ = fmaf(XV[1].w, wq[1][1].w, d1_); \
    d0_ = fmaf(XV[2].x, wq[0][2].x, d0_); d1_ = fmaf(XV[2].x, wq[1][2].x, d1_); \
    d0_ = fmaf(XV[2].y, wq[0][2].y, d0_); d1_ = fmaf(XV[2].y, wq[1][2].y, d1_); \
    d0_ = fmaf(XV[2].z, wq[0][2].z, d0_); d1_ = fmaf(XV[2].z, wq[1][2].z, d1_); \
    d0_ = fmaf(XV[2].w, wq[0][2].w, d0_); d1_ = fmaf(XV[2].w, wq[1][2].w, d1_); \
    float u_ = l1 ? d1_ : d0_;                                      \
    float v_ = l1 ? d0_ : d1_;                                      \
    float s_ = u_ + __shfl_xor(v_, 1);                              \
    s_ += __shfl_xor(s_, 2);                                        \
    s_ += __shfl_xor(s_, 4);                                        \
    s_ += __shfl_xor(s_, 8);                                        \
    s_ += __shfl_xor(s_, 16);                                       \
    s_ += __shfl_xor(s_, 32);                                       \
    float w_ = __expf(s_ - 20.f);   /* head h0+(lane&1) */          \
    sreg += w_;                                                     \
    float wo_ = __shfl_xor(w_, 1);                                  \
    float w0_ = l1 ? wo_ : w_;                                      \
    float w1_ = l1 ? w_ : wo_;                                      \
    acc[0][0].x = fmaf(w0_, XV[0].x, acc[0][0].x);                  \
    acc[0][0].y = fmaf(w0_, XV[0].y, acc[0][0].y);                  \
    acc[0][0].z = fmaf(w0_, XV[0].z, acc[0][0].z);                  \
    acc[0][0].w = fmaf(w0_, XV[0].w, acc[0][0].w);                  \
    acc[0][1].x = fmaf(w0_, XV[1].x, acc[0][1].x);                  \
    acc[0][1].y = fmaf(w0_, XV[1].y, acc[0][1].y);                  \
    acc[0][1].z = fmaf(w0_, XV[1].z, acc[0][1].z);                  \
    acc[0][1].w = fmaf(w0_, XV[1].w, acc[0][1].w);                  \
    acc[0][2].x = fmaf(w0_, XV[2].x, acc[0][2].x);                  \
    acc[0][2].y = fmaf(w0_, XV[2].y, acc[0][2].y);                  \
    acc[0][2].z = fmaf(w0_, XV[2].z, acc[0][2].z);                  \
    acc[0][2].w = fmaf(w0_, XV[2].w, acc[0][2].w);                  \
    acc[1][0].x = fmaf(w1_, XV[0].x, acc[1][0].x);                  \
    acc[1][0].y = fmaf(w1_, XV[0].y, acc[1][0].y);                  \
    acc[1][0].z = fmaf(w1_, XV[0].z, acc[1][0].z);                  \
    acc[1][0].w = fmaf(w1_, XV[0].w, acc[1][0].w);                  \
    acc[1][1].x = fmaf(w1_, XV[1].x, acc[1][1].x);                  \
    acc[1][1].y = fmaf(w1_, XV[1].y, acc[1][1].y);                  \
    acc[1][1].z = fmaf(w1_, XV[1].z, acc[1][1].z);                  \
    acc[1][1].w = fmaf(w1_, XV[1].w, acc[1][1].w);                  \
    acc[1][2].x = fmaf(w1_, XV[2].x, acc[1][2].x);                  \
    acc[1][2].y = fmaf(w1_, XV[2].y, acc[1][2].y);                  \
    acc[1][2].z = fmaf(w1_, XV[2].z, acc[1][2].z);                  \
    acc[1][2].w = fmaf(w1_, XV[2].w, acc[1][2].w);                  \
  } while (0)

  float4 xvA[3], xvB[3];
  LOADROW(xvA, 0);
  for (int r = 0; r < RPS; r += 2) {
    LOADROW(xvB, r + 1);
    PROC(xvA);
    if (r + 2 < RPS) LOADROW(xvA, r + 2);
    PROC(xvB);
    if ((r & 15) == 14) BARL();   // drift control only (keeps L1/L2 sharing hot)
  }

  // epilogue: slice partials for this wave's 2 heads + denominators
  float* pp = part + (((size_t)b * NSL + sl) * H_ + h0) * C_;
#pragma unroll
  for (int hh = 0; hh < 2; ++hh)
#pragma unroll
    for (int p = 0; p < 3; ++p)
      *(float4*)(pp + (size_t)hh * C_ + p * 256 + col) = acc[hh][p];
  if (lane < 2) sout[((size_t)b * NSL + sl) * H_ + h0 + lane] = sreg;
#undef LOADROW
#undef PROC
}

// ---- combout: (h,b) combines NSL slice partials, out1 slice ---------------
__global__ __launch_bounds__(256) void k_combout(
    const float* __restrict__ part, const float* __restrict__ spart,
    const float* __restrict__ Wkv, float* __restrict__ out1) {
  __shared__ __align__(16) float xb[C_];
  const int h = blockIdx.x, b = blockIdx.y;
  const int tid = threadIdx.x, lane = tid & 63, wv = tid >> 6;

  const float* sp = spart + (size_t)b * NSL * H_ + h;
  float den = 0.f;
#pragma unroll
  for (int ch = 0; ch < NSL; ++ch) den += sp[(size_t)ch * H_];
  const float inv = 1.f / den;

  const int c0 = tid * 3;
  const float* pp = part + ((size_t)(b * NSL) * H_ + h) * C_ + c0;
  float a0 = 0.f, a1 = 0.f, a2 = 0.f;
#pragma unroll
  for (int ch = 0; ch < NSL; ++ch) {
    const float* p = pp + (size_t)ch * H_ * C_;
    a0 += p[0]; a1 += p[1]; a2 += p[2];
  }
  xb[c0] = a0 * inv; xb[c0 + 1] = a1 * inv; xb[c0 + 2] = a2 * inv;
  __syncthreads();

  float4 x0 = *(const float4*)(&xb[lane * 4]);
  float4 x1 = *(const float4*)(&xb[256 + lane * 4]);
  float4 x2 = *(const float4*)(&xb[512 + lane * 4]);
#pragma unroll 4
  for (int j = 0; j < 24; ++j) {
    int e = h * DH_ + wv * 24 + j;
    const float* wr = Wkv + (size_t)(C_ + e) * C_ + lane * 4;
    float4 w0 = *(const float4*)(wr);
    float4 w1 = *(const float4*)(wr + 256);
    float4 w2 = *(const float4*)(wr + 512);
    float a = w0.x * x0.x;
    a = fmaf(w0.y, x0.y, a); a = fmaf(w0.z, x0.z, a); a = fmaf(w0.w, x0.w, a);
    a = fmaf(w1.x, x1.x, a); a = fmaf(w1.y, x1.y, a);
    a = fmaf(w1.z, x1.z, a); a = fmaf(w1.w, x1.w, a);
    a = fmaf(w2.x, x2.x, a); a = fmaf(w2.y, x2.y, a);
    a = fmaf(w2.z, x2.z, a); a = fmaf(w2.w, x2.w, a);
#pragma unroll
    for (int off = 32; off; off >>= 1) a += __shfl_xor(a, off);
    if (lane == 0) out1[(size_t)b * C_ + e] = a;
  }
}

// ---- proj (validated R12) --------------------------------------------------
__global__ __launch_bounds__(256) void k_proj2(
    const float* __restrict__ out1, const float* __restrict__ Wproj,
    const float* __restrict__ bproj, float* __restrict__ y) {
  __shared__ __align__(16) float xb[C_];
  const int esl = blockIdx.x, b = blockIdx.y;
  const int tid = threadIdx.x, lane = tid & 63, wv = tid >> 6;

  if (tid < 192) ((float4*)xb)[tid] = ((const float4*)(out1 + (size_t)b * C_))[tid];
  __syncthreads();

  float4 x0 = *(const float4*)(&xb[lane * 4]);
  float4 x1 = *(const float4*)(&xb[256 + lane * 4]);
  float4 x2 = *(const float4*)(&xb[512 + lane * 4]);
#pragma unroll 4
  for (int j = 0; j < 24; ++j) {
    int e = esl * DH_ + wv * 24 + j;
    const float* wr = Wproj + (size_t)e * C_ + lane * 4;
    float4 w0 = *(const float4*)(wr);
    float4 w1 = *(const float4*)(wr + 256);
    float4 w2 = *(const float4*)(wr + 512);
    float a = w0.x * x0.x;
    a = fmaf(w0.y, x0.y, a); a = fmaf(w0.z, x0.z, a); a = fmaf(w0.w, x0.w, a);
    a = fmaf(w1.x, x1.x, a); a = fmaf(w1.y, x1.y, a);
    a = fmaf(w1.z, x1.z, a); a = fmaf(w1.w, x1.w, a);
    a = fmaf(w2.x, x2.x, a); a = fmaf(w2.y, x2.y, a);
    a = fmaf(w2.z, x2.z, a); a = fmaf(w2.w, x2.w, a);
#pragma unroll
    for (int off = 32; off; off >>= 1) a += __shfl_xor(a, off);
    if (lane == 0) y[(size_t)b * C_ + e] = a + bproj[e];
  }
}

extern "C" void kernel_launch(void* const* d_in, const int* in_sizes, int n_in,
                              void* d_out, int out_size, void* d_ws, size_t ws_size,
                              hipStream_t stream) {
  const float* x       = (const float*)d_in[0];
  const float* queries = (const float*)d_in[1];
  const float* Wq      = (const float*)d_in[2];
  const float* Wkv     = (const float*)d_in[3];
  const float* Wproj   = (const float*)d_in[4];
  const float* bproj   = (const float*)d_in[5];
  float* y  = (float*)d_out;
  float* ws = (float*)d_ws;

  float* wqep  = ws;                                   // NDG*H*C = 24576
  float* spart = ws + 24576;                           // B*NSL*H = 8192
  float* part  = ws + 32768;                           // B*NSL*H*C = 6291456
  float* out1  = part + (size_t)B_ * NSL * H_ * C_;    // 24576

  hipLaunchKernelGGL(k_prep,    dim3(H_, NDG),  dim3(256), 0, stream, queries, Wq, Wkv, wqep);
  hipLaunchKernelGGL(k_stream,  dim3(NSL, B_),  dim3(256), 0, stream, x, wqep, part, spart);
  hipLaunchKernelGGL(k_combout, dim3(H_, B_),   dim3(256), 0, stream, part, spart, Wkv, out1);
  hipLaunchKernelGGL(k_proj2,   dim3(H_, B_),   dim3(256), 0, stream, out1, Wproj, bproj, y);
}